// Round 4
// baseline (331.815 us; speedup 1.0000x reference)
//
#include <hip/hip_runtime.h>
#include <stdint.h>

#define EPSF 1e-20f

typedef __attribute__((ext_vector_type(4))) int i32x4;
typedef __attribute__((ext_vector_type(8))) int i32x8;
typedef __attribute__((ext_vector_type(16))) float f32x16;

// ===========================================================================
// PATH A (primary): binarize to ±1 FP4 (e2m1) + mfma_scale f8f6f4 GEMM.
// Round 4: faithful m201-style 8-phase schedule (4 phases per K-tile,
// barrier PAIRS, lgkmcnt(0)+sched_barrier discipline, counted vmcnt once
// per half-tile, setprio per MFMA cluster). R1/R2/R3 all plateaued at
// 82 us = the documented m97-structure fp4 ceiling (~3400 TF).
// ===========================================================================

// fp32 -> packed fp4 nibbles, 8 floats per u32. Stores 4B/lane coalesced.
__global__ __launch_bounds__(256)
void bin_fp4_kernel(const float4* __restrict__ src, uint32_t* __restrict__ dst,
                    int n8) {
    int base = blockIdx.x * 1024 + threadIdx.x;   // u32 output index
#pragma unroll
    for (int j = 0; j < 4; ++j) {
        int idx = base + j * 256;
        if (idx < n8) {
            float4 v0 = src[2 * idx];
            float4 v1 = src[2 * idx + 1];
            // e2m1: +1.0 = 0b0010, -1.0 = 0b1010. Low nibble = lower K index.
            uint32_t w = 0;
            w |= ((v0.x < -EPSF) ? 0xAu : 0x2u);
            w |= ((v0.y < -EPSF) ? 0xAu : 0x2u) << 4;
            w |= ((v0.z < -EPSF) ? 0xAu : 0x2u) << 8;
            w |= ((v0.w < -EPSF) ? 0xAu : 0x2u) << 12;
            w |= ((v1.x < -EPSF) ? 0xAu : 0x2u) << 16;
            w |= ((v1.y < -EPSF) ? 0xAu : 0x2u) << 20;
            w |= ((v1.z < -EPSF) ? 0xAu : 0x2u) << 24;
            w |= ((v1.w < -EPSF) ? 0xAu : 0x2u) << 28;
            dst[idx] = w;
        }
    }
}

#define SCALE_ONE 0x7F7F7F7Fu  // e8m0 127 = 2^0 in every byte (opsel-proof)

#define MFMA4(A8, B8, ACC)                                                  \
    (ACC) = __builtin_amdgcn_mfma_scale_f32_32x32x64_f8f6f4(                \
        (A8), (B8), (ACC), 4, 4, 0, SCALE_ONE, 0, SCALE_ONE)

// 256x256 tile, 512 threads = 8 waves (2M x 4N), per-wave 128x64 output
// (acc[4][2] of 32x32). K-tile = 256 fp4 = 128 B/row; 16 K-tiles.
// LDS: dbuf[2] x (A 32KB | B 32KB) = 128 KiB, XOR chunk swizzle as before.
//
// Staging groups (8KB each, 1 load/thread): A0..A3 = 64-row blocks of A,
// B0..B3 = 64-row blocks of B. Issue schedule (for tile t+1, into nxt,
// 2 per phase):  P0: B0,B1   P1: B2,B3   P2: A0,A2   P3: A1,A3.
// nxt (= tile t-1's buffer) is fully dead once tile t starts (all t-1
// reads completed before t's first barrier), so any write order is safe.
//
// Per-wave read/consume plan per K-tile (phase = 8 MFMA = row-pair x col):
//   P0: read aF rows{0,1}x4m (8) + bF0 col0 x4m (4) -> MFMA acc[0..1][0]
//   P1: read bF1 col1 x4m (4)                       -> MFMA acc[0..1][1]
//   P2: read aF rows{2,3}x4m (8)                    -> MFMA acc[2..3][0]
//   P3: (no reads; all cached)                      -> MFMA acc[2..3][1]
// Phase body: reads+stages; sched_barrier; s_barrier; lgkmcnt(0);
// sched_barrier; setprio(1); 8 MFMA; setprio(0); [vmcnt] s_barrier.
//
// vmcnt ledger (per-wave FIFO; every wave issues every group):
//   P1-end: vmcnt(4)  -> allows {B0..B3 of t+1}; certifies A1,A3 of t
//           (needed by P2/P3). kt==15: no t+1 issues -> vmcnt(0).
//   P3-end: vmcnt(2)  -> allows {A1,A3 of t+1}; certifies B0..B3 + A0,A2
//           of t+1 (needed by next tile's P0/P1).
__global__ __launch_bounds__(512, 2)
void fp4mfma_gemm256(const char* __restrict__ x4, const char* __restrict__ w4,
                     float* __restrict__ out) {
    __shared__ char lds[2][65536];   // [buf][ A: 0..32767 | B: 32768..65535 ]

    const int t = threadIdx.x;
    const int lane = t & 63;
    const int wave = t >> 6;
    const int wm = (wave >> 2) * 128;   // 0 or 128
    const int wn = (wave & 3) * 64;     // 0,64,128,192
    const int row0 = blockIdx.y * 256;
    const int col0 = blockIdx.x * 256;
    const int lrow = lane & 31;
    const int half = lane >> 5;

    const char* xbase = x4 + (size_t)row0 * 2048;  // 2048 B = 4096 fp4 per row
    const char* wbase = w4 + (size_t)col0 * 2048;

    // Staging per-thread constants (row = g*64 + (t>>3) within group g).
    const int srow = t >> 3;                   // 0..63 within a 64-row group
    const int sqg  = (t & 7) ^ (srow & 7);     // source chunk for LDS slot t&7
    const int gsrc = srow * 2048 + sqg * 16;   // + g*131072 + kb
    const int gdst = t * 16;                   // + g*8192  (linear in lane)

    f32x16 acc[4][2];
#pragma unroll
    for (int r = 0; r < 4; ++r)
#pragma unroll
        for (int c = 0; c < 2; ++c)
#pragma unroll
            for (int e = 0; e < 16; ++e) acc[r][c][e] = 0.0f;

    // Working MFMA operand tuples (FP4: low 4 regs data, upper 4 zero).
    i32x8 a8[2], b8;
#pragma unroll
    for (int e = 0; e < 8; ++e) { a8[0][e] = 0; a8[1][e] = 0; b8[e] = 0; }

    // Register fragment caches.
    i32x4 aF[2][4];   // A row-pair (rows {0,1} or {2,3}) x 4 k-slices
    i32x4 bF0[4];     // B col0 x 4 k-slices (live P0..P2)
    i32x4 bF1[4];     // B col1 x 4 k-slices (live P1..P3)

    // Per-slice swizzled chunk offset (row&7 == lrow&7 for all our rows).
    int qs16[4];
#pragma unroll
    for (int m = 0; m < 4; ++m)
        qs16[m] = (((2 * m + half) ^ (lrow & 7)) << 4);

    const int aoff = (wm + lrow) * 128;   // + fragrow*4096 + qs16[m]
    const int boff = 32768 + (wn + lrow) * 128;

#define ISSUE_A(buf, g, kb)                                                   \
    __builtin_amdgcn_global_load_lds(                                         \
        (const uint32_t*)(xbase + (g) * 131072 + gsrc + (kb)),                \
        (uint32_t*)((buf) + (g) * 8192 + gdst), 16, 0, 0)
#define ISSUE_B(buf, g, kb)                                                   \
    __builtin_amdgcn_global_load_lds(                                         \
        (const uint32_t*)(wbase + (g) * 131072 + gsrc + (kb)),                \
        (uint32_t*)((buf) + 32768 + (g) * 8192 + gdst), 16, 0, 0)

    // Prologue: stage tile 0 in the exact steady-state issue order, then
    // publish everything P0/P1 need (all but A1,A3 -> vmcnt(2)).
    {
        char* b0 = &lds[0][0];
        ISSUE_B(b0, 0, 0); ISSUE_B(b0, 1, 0); ISSUE_B(b0, 2, 0); ISSUE_B(b0, 3, 0);
        ISSUE_A(b0, 0, 0); ISSUE_A(b0, 2, 0); ISSUE_A(b0, 1, 0); ISSUE_A(b0, 3, 0);
    }
    asm volatile("s_waitcnt vmcnt(2)" ::: "memory");
    __builtin_amdgcn_s_barrier();

    for (int kt = 0; kt < 16; ++kt) {
        const char* cb = &lds[kt & 1][0];
        char* nb = &lds[(kt & 1) ^ 1][0];
        const int kb = (kt + 1) * 128;
        const bool st = (kt < 15);

        // ================= P0: acc[0..1][0] =================
#pragma unroll
        for (int m = 0; m < 4; ++m) {
            aF[0][m] = *(const i32x4*)(cb + aoff + 0 * 4096 + qs16[m]);
            aF[1][m] = *(const i32x4*)(cb + aoff + 1 * 4096 + qs16[m]);
            bF0[m]   = *(const i32x4*)(cb + boff + 0 * 4096 + qs16[m]);
        }
        if (st) { ISSUE_B(nb, 0, kb); ISSUE_B(nb, 1, kb); }
        __builtin_amdgcn_sched_barrier(0);
        __builtin_amdgcn_s_barrier();
        asm volatile("s_waitcnt lgkmcnt(0)" ::: "memory");
        __builtin_amdgcn_sched_barrier(0);
        __builtin_amdgcn_s_setprio(1);
#pragma unroll
        for (int m = 0; m < 4; ++m) {
            *(i32x4*)&a8[0] = aF[0][m];
            *(i32x4*)&a8[1] = aF[1][m];
            *(i32x4*)&b8 = bF0[m];
            MFMA4(a8[0], b8, acc[0][0]);
            MFMA4(a8[1], b8, acc[1][0]);
        }
        __builtin_amdgcn_s_setprio(0);
        __builtin_amdgcn_s_barrier();

        // ================= P1: acc[0..1][1] =================
#pragma unroll
        for (int m = 0; m < 4; ++m)
            bF1[m] = *(const i32x4*)(cb + boff + 1 * 4096 + qs16[m]);
        if (st) { ISSUE_B(nb, 2, kb); ISSUE_B(nb, 3, kb); }
        __builtin_amdgcn_sched_barrier(0);
        __builtin_amdgcn_s_barrier();
        asm volatile("s_waitcnt lgkmcnt(0)" ::: "memory");
        __builtin_amdgcn_sched_barrier(0);
        __builtin_amdgcn_s_setprio(1);
#pragma unroll
        for (int m = 0; m < 4; ++m) {
            *(i32x4*)&a8[0] = aF[0][m];
            *(i32x4*)&a8[1] = aF[1][m];
            *(i32x4*)&b8 = bF1[m];
            MFMA4(a8[0], b8, acc[0][1]);
            MFMA4(a8[1], b8, acc[1][1]);
        }
        __builtin_amdgcn_s_setprio(0);
        if (st) { asm volatile("s_waitcnt vmcnt(4)" ::: "memory"); }
        else    { asm volatile("s_waitcnt vmcnt(0)" ::: "memory"); }
        __builtin_amdgcn_s_barrier();

        // ================= P2: acc[2..3][0] =================
#pragma unroll
        for (int m = 0; m < 4; ++m) {
            aF[0][m] = *(const i32x4*)(cb + aoff + 2 * 4096 + qs16[m]);
            aF[1][m] = *(const i32x4*)(cb + aoff + 3 * 4096 + qs16[m]);
        }
        if (st) { ISSUE_A(nb, 0, kb); ISSUE_A(nb, 2, kb); }
        __builtin_amdgcn_sched_barrier(0);
        __builtin_amdgcn_s_barrier();
        asm volatile("s_waitcnt lgkmcnt(0)" ::: "memory");
        __builtin_amdgcn_sched_barrier(0);
        __builtin_amdgcn_s_setprio(1);
#pragma unroll
        for (int m = 0; m < 4; ++m) {
            *(i32x4*)&a8[0] = aF[0][m];
            *(i32x4*)&a8[1] = aF[1][m];
            *(i32x4*)&b8 = bF0[m];
            MFMA4(a8[0], b8, acc[2][0]);
            MFMA4(a8[1], b8, acc[3][0]);
        }
        __builtin_amdgcn_s_setprio(0);
        __builtin_amdgcn_s_barrier();

        // ================= P3: acc[2..3][1] =================
        if (st) { ISSUE_A(nb, 1, kb); ISSUE_A(nb, 3, kb); }
        __builtin_amdgcn_sched_barrier(0);
        __builtin_amdgcn_s_barrier();
        __builtin_amdgcn_sched_barrier(0);
        __builtin_amdgcn_s_setprio(1);
#pragma unroll
        for (int m = 0; m < 4; ++m) {
            *(i32x4*)&a8[0] = aF[0][m];
            *(i32x4*)&a8[1] = aF[1][m];
            *(i32x4*)&b8 = bF1[m];
            MFMA4(a8[0], b8, acc[2][1]);
            MFMA4(a8[1], b8, acc[3][1]);
        }
        __builtin_amdgcn_s_setprio(0);
        if (st) { asm volatile("s_waitcnt vmcnt(2)" ::: "memory"); }
        __builtin_amdgcn_s_barrier();
    }
#undef ISSUE_A
#undef ISSUE_B

    // C/D layout (32x32, shape-determined, dtype-independent):
    // col = lane&31, row = (reg&3) + 8*(reg>>2) + 4*(lane>>5)
#pragma unroll
    for (int r = 0; r < 4; ++r)
#pragma unroll
        for (int c = 0; c < 2; ++c)
#pragma unroll
            for (int e = 0; e < 16; ++e) {
                int rr = row0 + wm + r * 32 + (e & 3) + 8 * (e >> 2) + 4 * half;
                int cc = col0 + wn + c * 32 + lrow;
                out[(size_t)rr * 4096 + cc] = acc[r][c][e];
            }
}

// ===========================================================================
// PATH B (fallback if ws_size too small): R1 bit-pack + XOR/popcount GEMM
// (verified correct) — kept verbatim for safety.
// ===========================================================================

__global__ __launch_bounds__(256)
void binarize_kernel(const float* __restrict__ src,
                     unsigned long long* __restrict__ dst, int n256) {
    int wave = blockIdx.x * 4 + (threadIdx.x >> 6);
    if (wave >= n256) return;
    int lane = threadIdx.x & 63;
    const float4* p = (const float4*)(src + (size_t)wave * 256);
    float4 v = p[lane];
    unsigned long long m0 = __ballot(v.x < -EPSF);
    unsigned long long m1 = __ballot(v.y < -EPSF);
    unsigned long long m2 = __ballot(v.z < -EPSF);
    unsigned long long m3 = __ballot(v.w < -EPSF);
    if (lane < 4) {
        unsigned long long m = (lane == 0) ? m0 : (lane == 1) ? m1
                             : (lane == 2) ? m2 : m3;
        dst[(size_t)wave * 4 + lane] = m;
    }
}

#define BM 128
#define BN 128
#define CHUNK_Q 8
#define NCHUNK 4
#define LDSS 9

__global__ __launch_bounds__(256, 2)
void bingemm_kernel(const uint4* __restrict__ xb, const uint4* __restrict__ wb,
                    float* __restrict__ out) {
    __shared__ uint4 xsl[BM * LDSS];
    __shared__ uint4 wsl[BN * LDSS];

    const int t  = threadIdx.x;
    const int tx = t & 15;
    const int ty = t >> 4;
    const int row0 = blockIdx.y * BM;
    const int col0 = blockIdx.x * BN;

    int acc[8][8];
#pragma unroll
    for (int a = 0; a < 8; ++a)
#pragma unroll
        for (int b = 0; b < 8; ++b) acc[a][b] = 0;

    const int srow = t >> 3;
    const int sq   = t & 7;

    for (int c = 0; c < NCHUNK; ++c) {
        __syncthreads();
#pragma unroll
        for (int k = 0; k < 4; ++k) {
            int r = srow + 32 * k;
            xsl[r * LDSS + sq] = xb[(size_t)(row0 + r) * 32 + c * CHUNK_Q + sq];
            wsl[r * LDSS + sq] = wb[(size_t)(col0 + r) * 32 + c * CHUNK_Q + sq];
        }
        __syncthreads();

#pragma unroll
        for (int q = 0; q < CHUNK_Q; ++q) {
            uint4 xq[8], wq[8];
#pragma unroll
            for (int ri = 0; ri < 8; ++ri)
                xq[ri] = xsl[(ty + 16 * ri) * LDSS + q];
#pragma unroll
            for (int cj = 0; cj < 8; ++cj)
                wq[cj] = wsl[(tx + 16 * cj) * LDSS + q];
#pragma unroll
            for (int ri = 0; ri < 8; ++ri)
#pragma unroll
                for (int cj = 0; cj < 8; ++cj) {
                    acc[ri][cj] += __builtin_popcount(xq[ri].x ^ wq[cj].x);
                    acc[ri][cj] += __builtin_popcount(xq[ri].y ^ wq[cj].y);
                    acc[ri][cj] += __builtin_popcount(xq[ri].z ^ wq[cj].z);
                    acc[ri][cj] += __builtin_popcount(xq[ri].w ^ wq[cj].w);
                }
        }
    }

#pragma unroll
    for (int ri = 0; ri < 8; ++ri) {
        size_t i = row0 + ty + 16 * ri;
#pragma unroll
        for (int cj = 0; cj < 8; ++cj) {
            int j = col0 + tx + 16 * cj;
            out[i * 4096 + j] = (float)(4096 - 2 * acc[ri][cj]);
        }
    }
}

// ===========================================================================
extern "C" void kernel_launch(void* const* d_in, const int* in_sizes, int n_in,
                              void* d_out, int out_size, void* d_ws, size_t ws_size,
                              hipStream_t stream) {
    const float* x = (const float*)d_in[0];   // [8192, 4096] fp32
    const float* w = (const float*)d_in[1];   // [4096, 4096] fp32
    float* out = (float*)d_out;

    const int M = 8192, N = 4096, K = 4096;
    const size_t need_fp4 = ((size_t)M * K + (size_t)N * K) / 2;  // 25.2 MB

    if (ws_size >= need_fp4) {
        char* x4 = (char*)d_ws;
        char* w4 = x4 + (size_t)M * K / 2;

        int n8x = (M * K) / 8;   // 4194304 u32 -> 4096 blocks
        int n8w = (N * K) / 8;   // 2097152 u32 -> 2048 blocks
        bin_fp4_kernel<<<n8x / 1024, 256, 0, stream>>>(
            (const float4*)x, (uint32_t*)x4, n8x);
        bin_fp4_kernel<<<n8w / 1024, 256, 0, stream>>>(
            (const float4*)w, (uint32_t*)w4, n8w);

        dim3 grid(N / 256, M / 256);  // (16, 32) = 512 blocks
        fp4mfma_gemm256<<<grid, 512, 0, stream>>>(x4, w4, out);
    } else {
        uint32_t* xbits = (uint32_t*)d_ws;
        uint32_t* wbits = xbits + (size_t)M * (K / 32);

        binarize_kernel<<<(M * K) / 1024, 256, 0, stream>>>(
            x, (unsigned long long*)xbits, (M * K) / 256);
        binarize_kernel<<<(N * K) / 1024, 256, 0, stream>>>(
            w, (unsigned long long*)wbits, (N * K) / 256);

        dim3 grid(N / BN, M / BM);
        bingemm_kernel<<<grid, 256, 0, stream>>>(
            (const uint4*)xbits, (const uint4*)wbits, out);
    }
}